// Round 1
// baseline (322.514 us; speedup 1.0000x reference)
//
#include <hip/hip_runtime.h>
#include <hip/hip_bf16.h>
#include <math.h>

// Problem constants (B=2, T=2048, C=1024, NH=16, HS=64)
#define BB   2
#define TT   2048
#define CC   1024
#define NH   16
#define HS   64
#define N3C  3072   // 3*C
#define MM   4096   // B*T

typedef __attribute__((ext_vector_type(8))) short bf16x8;
typedef __attribute__((ext_vector_type(4))) float f32x4;

__device__ __forceinline__ unsigned short f2bf(float f) {
    unsigned int u = __builtin_bit_cast(unsigned int, f);
    unsigned int r = u + 0x7fffu + ((u >> 16) & 1u);   // RNE
    return (unsigned short)(r >> 16);
}

// ---------------- cast x (fp32) -> xb (bf16) ----------------
__global__ __launch_bounds__(256) void k_cast(const float* __restrict__ x,
                                              unsigned short* __restrict__ xb) {
    int i = (blockIdx.x * 256 + threadIdx.x) * 4;
    float4 v = *(const float4*)(x + i);
    ushort4 o;
    o.x = f2bf(v.x); o.y = f2bf(v.y); o.z = f2bf(v.z); o.w = f2bf(v.w);
    *(ushort4*)(xb + i) = o;
}

// ---------------- transpose+cast W [K=1024, N=3072] -> Wt [N, K] bf16 ----------------
__global__ __launch_bounds__(256) void k_transpose_w(const float* __restrict__ W,
                                                     unsigned short* __restrict__ Wt) {
    __shared__ float tile[32][33];
    const int n0 = blockIdx.x * 32;
    const int k0 = blockIdx.y * 32;
    const int t = threadIdx.x;
    {
        int kr = t >> 3, ns = (t & 7) * 4;
        float4 v = *(const float4*)(W + (size_t)(k0 + kr) * N3C + n0 + ns);
        tile[kr][ns + 0] = v.x; tile[kr][ns + 1] = v.y;
        tile[kr][ns + 2] = v.z; tile[kr][ns + 3] = v.w;
    }
    __syncthreads();
    {
        int nr = t >> 3, ks = (t & 7) * 4;
        ushort4 o;
        o.x = f2bf(tile[ks + 0][nr]);
        o.y = f2bf(tile[ks + 1][nr]);
        o.z = f2bf(tile[ks + 2][nr]);
        o.w = f2bf(tile[ks + 3][nr]);
        *(ushort4*)(Wt + (size_t)(n0 + nr) * CC + k0 + ks) = o;
    }
}

// ---------------- GEMM: qkv = xb @ Wt^T + bias, scattered into q/k/vT layouts ----------------
// Tile 64x64, block = 256 threads (4 waves); wave w computes rows [16w,16w+16) x 64 cols.
__global__ __launch_bounds__(256) void k_gemm_qkv(const unsigned short* __restrict__ xb,
                                                  const unsigned short* __restrict__ wt,
                                                  const float* __restrict__ bias,
                                                  unsigned short* __restrict__ qb,
                                                  unsigned short* __restrict__ kb,
                                                  unsigned short* __restrict__ vt) {
    __shared__ unsigned short sA[64 * 32];
    __shared__ unsigned short sB[64 * 32];
    const int t = threadIdx.x;
    const int wave = t >> 6, lane = t & 63;
    const int quad = lane >> 4, c16 = lane & 15;
    const int m0 = blockIdx.y * 64;
    const int n0 = blockIdx.x * 64;

    f32x4 acc[4] = {f32x4{0,0,0,0}, f32x4{0,0,0,0}, f32x4{0,0,0,0}, f32x4{0,0,0,0}};

    const int srow = t >> 2, soff = (t & 3) * 8;
    const unsigned short* xrow = xb + (size_t)(m0 + srow) * CC + soff;
    const unsigned short* wrow = wt + (size_t)(n0 + srow) * CC + soff;

    for (int k0 = 0; k0 < CC; k0 += 32) {
        __syncthreads();
        *(bf16x8*)(sA + srow * 32 + soff) = *(const bf16x8*)(xrow + k0);
        *(bf16x8*)(sB + srow * 32 + soff) = *(const bf16x8*)(wrow + k0);
        __syncthreads();
        bf16x8 a = *(const bf16x8*)(sA + (wave * 16 + c16) * 32 + quad * 8);
#pragma unroll
        for (int c = 0; c < 4; ++c) {
            bf16x8 b = *(const bf16x8*)(sB + (c * 16 + c16) * 32 + quad * 8);
            acc[c] = __builtin_amdgcn_mfma_f32_16x16x32_bf16(a, b, acc[c], 0, 0, 0);
        }
    }

    // Epilogue: bias + scatter to q [bh,t,d], k [bh,t,d], vT [bh,d,t] (bf16)
#pragma unroll
    for (int c = 0; c < 4; ++c) {
        const int n = n0 + c * 16 + c16;
        const float bv = bias[n];
        const int sel = n >> 10;         // 0=q, 1=k, 2=v
        const int head = (n >> 6) & 15;
        const int d = n & 63;
#pragma unroll
        for (int r = 0; r < 4; ++r) {
            const int m = m0 + wave * 16 + quad * 4 + r;
            const int b_ = m >> 11;       // m / T
            const int tt = m & 2047;      // m % T
            const int bh = b_ * NH + head;
            const unsigned short hv = f2bf(acc[c][r] + bv);
            if (sel == 0)      qb[((size_t)bh * TT + tt) * HS + d] = hv;
            else if (sel == 1) kb[((size_t)bh * TT + tt) * HS + d] = hv;
            else               vt[((size_t)bh * HS + d) * TT + tt] = hv;
        }
    }
}

// ---------------- Flash attention: one block = (b,h, 64 q-rows); 4 waves x 16 q-rows ----------------
__global__ __launch_bounds__(256) void k_attn(const unsigned short* __restrict__ qb,
                                              const unsigned short* __restrict__ kb,
                                              const unsigned short* __restrict__ vt,
                                              float* __restrict__ out) {
    __shared__ unsigned short sK[32 * 64];       // K[tk][d]
    __shared__ unsigned short sV[64 * 32];       // V^T[d][tk]
    __shared__ unsigned short sP[4 * 16 * 32];   // per-wave P tile (bf16)

    const int t = threadIdx.x;
    const int wave = t >> 6, lane = t & 63;
    const int quad = lane >> 4, c16 = lane & 15;
    const int qblk = blockIdx.x & 31;            // T/64 = 32 q-blocks
    const int bh   = blockIdx.x >> 5;            // 0..31
    const int q0 = qblk * 64;

    const unsigned short* Qp = qb + (size_t)bh * TT * HS;
    const unsigned short* Kp = kb + (size_t)bh * TT * HS;
    const unsigned short* Vp = vt + (size_t)bh * HS * TT;

    // Q fragments for this wave's 16 rows (A-layout: m=c16, k=quad*8+j)
    const int qrow = q0 + wave * 16 + c16;
    const bf16x8 qf0 = *(const bf16x8*)(Qp + (size_t)qrow * HS + quad * 8);
    const bf16x8 qf1 = *(const bf16x8*)(Qp + (size_t)qrow * HS + 32 + quad * 8);

    f32x4 o[4] = {f32x4{0,0,0,0}, f32x4{0,0,0,0}, f32x4{0,0,0,0}, f32x4{0,0,0,0}};
    float mprev[4] = {-__builtin_inff(), -__builtin_inff(), -__builtin_inff(), -__builtin_inff()};
    float lsum[4]  = {0.f, 0.f, 0.f, 0.f};

    const int srowK = t >> 3, soffK = (t & 7) * 8;   // 32 rows x 64 cols
    const int srowV = t >> 2, soffV = (t & 3) * 8;   // 64 rows x 32 cols

    const int kend = q0 + 64;
    for (int kb0 = 0; kb0 < kend; kb0 += 32) {
        __syncthreads();
        *(bf16x8*)(sK + srowK * 64 + soffK) = *(const bf16x8*)(Kp + (size_t)(kb0 + srowK) * HS + soffK);
        *(bf16x8*)(sV + srowV * 32 + soffV) = *(const bf16x8*)(Vp + (size_t)srowV * TT + kb0 + soffV);
        __syncthreads();

        // S = Q K^T for 32 k-columns: two 16x16 col-tiles, two 32-deep k-steps over HS
        f32x4 s0 = {0,0,0,0}, s1 = {0,0,0,0};
        {
            bf16x8 kf;
            kf = *(const bf16x8*)(sK + c16 * 64 + quad * 8);
            s0 = __builtin_amdgcn_mfma_f32_16x16x32_bf16(qf0, kf, s0, 0, 0, 0);
            kf = *(const bf16x8*)(sK + c16 * 64 + 32 + quad * 8);
            s0 = __builtin_amdgcn_mfma_f32_16x16x32_bf16(qf1, kf, s0, 0, 0, 0);
            kf = *(const bf16x8*)(sK + (16 + c16) * 64 + quad * 8);
            s1 = __builtin_amdgcn_mfma_f32_16x16x32_bf16(qf0, kf, s1, 0, 0, 0);
            kf = *(const bf16x8*)(sK + (16 + c16) * 64 + 32 + quad * 8);
            s1 = __builtin_amdgcn_mfma_f32_16x16x32_bf16(qf1, kf, s1, 0, 0, 0);
        }

        // Online softmax update (rows live across 16 lanes of each quad-group)
        const int col0 = kb0 + c16, col1 = kb0 + 16 + c16;
        float p0[4], p1[4], alpha[4];
#pragma unroll
        for (int r = 0; r < 4; ++r) {
            const int row = q0 + wave * 16 + quad * 4 + r;
            float v0 = s0[r] * 0.125f; if (col0 > row) v0 = -__builtin_inff();
            float v1 = s1[r] * 0.125f; if (col1 > row) v1 = -__builtin_inff();
            float mx = fmaxf(v0, v1);
            mx = fmaxf(mx, __shfl_xor(mx, 1, 16));
            mx = fmaxf(mx, __shfl_xor(mx, 2, 16));
            mx = fmaxf(mx, __shfl_xor(mx, 4, 16));
            mx = fmaxf(mx, __shfl_xor(mx, 8, 16));
            const float mc = fmaxf(mprev[r], mx);   // finite after first tile (col 0 always visible)
            const float a_ = __expf(mprev[r] - mc);
            const float e0 = __expf(v0 - mc);
            const float e1 = __expf(v1 - mc);
            float rs = e0 + e1;
            rs += __shfl_xor(rs, 1, 16);
            rs += __shfl_xor(rs, 2, 16);
            rs += __shfl_xor(rs, 4, 16);
            rs += __shfl_xor(rs, 8, 16);
            lsum[r] = lsum[r] * a_ + rs;
            mprev[r] = mc;
            alpha[r] = a_; p0[r] = e0; p1[r] = e1;
        }
        // Rescale O accumulator
#pragma unroll
        for (int dt = 0; dt < 4; ++dt) {
#pragma unroll
            for (int r = 0; r < 4; ++r) o[dt][r] *= alpha[r];
        }
        // P (C-layout) -> LDS -> A-layout fragment (per-wave region; no cross-wave barrier needed)
        unsigned short* pw = sP + wave * 512;
#pragma unroll
        for (int r = 0; r < 4; ++r) {
            pw[(quad * 4 + r) * 32 + c16]      = f2bf(p0[r]);
            pw[(quad * 4 + r) * 32 + 16 + c16] = f2bf(p1[r]);
        }
        const bf16x8 pf = *(const bf16x8*)(pw + c16 * 32 + quad * 8);
        // O += P @ V  (B-operand from V^T rows, contiguous in tk)
#pragma unroll
        for (int dt = 0; dt < 4; ++dt) {
            bf16x8 vf = *(const bf16x8*)(sV + (dt * 16 + c16) * 32 + quad * 8);
            o[dt] = __builtin_amdgcn_mfma_f32_16x16x32_bf16(pf, vf, o[dt], 0, 0, 0);
        }
    }

    // Write out[b][t][h*64+d], fp32
    const int b_ = bh >> 4, h_ = bh & 15;
#pragma unroll
    for (int dt = 0; dt < 4; ++dt) {
#pragma unroll
        for (int r = 0; r < 4; ++r) {
            const int row = q0 + wave * 16 + quad * 4 + r;
            out[((size_t)(b_ * TT + row)) * CC + h_ * HS + dt * 16 + c16] = o[dt][r] / lsum[r];
        }
    }
}

extern "C" void kernel_launch(void* const* d_in, const int* in_sizes, int n_in,
                              void* d_out, int out_size, void* d_ws, size_t ws_size,
                              hipStream_t stream) {
    const float* x    = (const float*)d_in[0];   // [B,T,C] fp32
    const float* W    = (const float*)d_in[1];   // [C,3C] fp32
    const float* bias = (const float*)d_in[2];   // [3C] fp32
    float* out = (float*)d_out;                  // [B,T,C] fp32

    char* ws = (char*)d_ws;
    // Workspace layout (bytes):
    //   xb: MM*CC*2      = 8388608
    //   wt: N3C*CC*2     = 6291456
    //   qb: MM*CC*2      = 8388608
    //   kb: MM*CC*2      = 8388608
    //   vt: MM*CC*2      = 8388608   (total ~38 MB)
    unsigned short* xb = (unsigned short*)(ws);
    unsigned short* wt = (unsigned short*)(ws + 8388608);
    unsigned short* qb = (unsigned short*)(ws + 8388608 + 6291456);
    unsigned short* kb = (unsigned short*)(ws + 8388608 + 6291456 + 8388608);
    unsigned short* vt = (unsigned short*)(ws + 8388608 + 6291456 + 2 * 8388608);

    k_cast<<<dim3(MM * CC / (256 * 4)), dim3(256), 0, stream>>>(x, xb);
    k_transpose_w<<<dim3(N3C / 32, CC / 32), dim3(256), 0, stream>>>(W, wt);
    k_gemm_qkv<<<dim3(N3C / 64, MM / 64), dim3(256), 0, stream>>>(xb, wt, bias, qb, kb, vt);
    k_attn<<<dim3(BB * NH * (TT / 64)), dim3(256), 0, stream>>>(qb, kb, vt, out);
}

// Round 2
// 236.753 us; speedup vs baseline: 1.3622x; 1.3622x over previous
//
#include <hip/hip_runtime.h>
#include <hip/hip_bf16.h>
#include <math.h>

// Problem constants (B=2, T=2048, C=1024, NH=16, HS=64)
#define BB   2
#define TT   2048
#define CC   1024
#define NH   16
#define HS   64
#define N3C  3072   // 3*C
#define MM   4096   // B*T

typedef __attribute__((ext_vector_type(8))) short bf16x8;
typedef __attribute__((ext_vector_type(4))) float f32x4;

__device__ __forceinline__ unsigned short f2bf(float f) {
    unsigned int u = __builtin_bit_cast(unsigned int, f);
    unsigned int r = u + 0x7fffu + ((u >> 16) & 1u);   // RNE
    return (unsigned short)(r >> 16);
}

// cheap round-to-nearest (no tie-to-even) — used only for P in [0,1]
__device__ __forceinline__ unsigned short f2bf_fast(float f) {
    unsigned int u = __builtin_bit_cast(unsigned int, f);
    return (unsigned short)((u + 0x8000u) >> 16);
}

// async 16B global -> LDS (dst must be wave-uniform base + lane*16)
__device__ __forceinline__ void gl_lds16(const unsigned short* g, unsigned short* l) {
    __builtin_amdgcn_global_load_lds(
        (const __attribute__((address_space(1))) unsigned int*)g,
        (__attribute__((address_space(3))) unsigned int*)l, 16, 0, 0);
}

// ---------------- cast x (fp32) -> xb (bf16) ----------------
__global__ __launch_bounds__(256) void k_cast(const float* __restrict__ x,
                                              unsigned short* __restrict__ xb) {
    int i = (blockIdx.x * 256 + threadIdx.x) * 4;
    float4 v = *(const float4*)(x + i);
    ushort4 o;
    o.x = f2bf(v.x); o.y = f2bf(v.y); o.z = f2bf(v.z); o.w = f2bf(v.w);
    *(ushort4*)(xb + i) = o;
}

// ---------------- transpose+cast W [K=1024, N=3072] -> Wt [N, K] bf16 ----------------
__global__ __launch_bounds__(256) void k_transpose_w(const float* __restrict__ W,
                                                     unsigned short* __restrict__ Wt) {
    __shared__ float tile[32][33];
    const int n0 = blockIdx.x * 32;
    const int k0 = blockIdx.y * 32;
    const int t = threadIdx.x;
    {
        int kr = t >> 3, ns = (t & 7) * 4;
        float4 v = *(const float4*)(W + (size_t)(k0 + kr) * N3C + n0 + ns);
        tile[kr][ns + 0] = v.x; tile[kr][ns + 1] = v.y;
        tile[kr][ns + 2] = v.z; tile[kr][ns + 3] = v.w;
    }
    __syncthreads();
    {
        int nr = t >> 3, ks = (t & 7) * 4;
        ushort4 o;
        o.x = f2bf(tile[ks + 0][nr]);
        o.y = f2bf(tile[ks + 1][nr]);
        o.z = f2bf(tile[ks + 2][nr]);
        o.w = f2bf(tile[ks + 3][nr]);
        *(ushort4*)(Wt + (size_t)(n0 + nr) * CC + k0 + ks) = o;
    }
}

// ---------------- GEMM (m97 structure): 128x128 tile, BK=32, global_load_lds staging ----------------
// qkv = xb @ Wt^T + bias; q scaled by 0.125 at write; scatter into q/k [bh,t,d], vT [bh,d,t].
__global__ __launch_bounds__(256) void k_gemm_qkv(const unsigned short* __restrict__ xb,
                                                  const unsigned short* __restrict__ wt,
                                                  const float* __restrict__ bias,
                                                  unsigned short* __restrict__ qb,
                                                  unsigned short* __restrict__ kb,
                                                  unsigned short* __restrict__ vt) {
    __shared__ unsigned short sA[128 * 32];   // 8 KB
    __shared__ unsigned short sB[128 * 32];   // 8 KB
    const int t = threadIdx.x;
    const int wave = t >> 6, lane = t & 63;
    const int quad = lane >> 4, c16 = lane & 15;
    const int wm = wave >> 1, wn = wave & 1;
    const int m0 = blockIdx.y * 128;
    const int n0 = blockIdx.x * 128;

    f32x4 acc[4][4];
#pragma unroll
    for (int i = 0; i < 4; ++i)
#pragma unroll
        for (int j = 0; j < 4; ++j) acc[i][j] = f32x4{0, 0, 0, 0};

    // staging source/dest (element offsets): lane l covers row (wave*16 + l>>2 + 64*round), col (l&3)*8
    const int srow = wave * 16 + (lane >> 2);
    const int scol = (lane & 3) * 8;
    const unsigned short* gA = xb + (size_t)(m0 + srow) * CC + scol;
    const unsigned short* gB = wt + (size_t)(n0 + srow) * CC + scol;
    unsigned short* lA = sA + wave * 512 + lane * 8;
    unsigned short* lB = sB + wave * 512 + lane * 8;

    for (int k0 = 0; k0 < CC; k0 += 32) {
        __syncthreads();
        gl_lds16(gA + k0, lA);
        gl_lds16(gA + k0 + (size_t)64 * CC, lA + 2048);
        gl_lds16(gB + k0, lB);
        gl_lds16(gB + k0 + (size_t)64 * CC, lB + 2048);
        __syncthreads();
        bf16x8 a[4], b[4];
#pragma unroll
        for (int rt = 0; rt < 4; ++rt)
            a[rt] = *(const bf16x8*)(sA + (wm * 64 + rt * 16 + c16) * 32 + quad * 8);
#pragma unroll
        for (int ct = 0; ct < 4; ++ct)
            b[ct] = *(const bf16x8*)(sB + (wn * 64 + ct * 16 + c16) * 32 + quad * 8);
#pragma unroll
        for (int rt = 0; rt < 4; ++rt)
#pragma unroll
            for (int ct = 0; ct < 4; ++ct)
                acc[rt][ct] = __builtin_amdgcn_mfma_f32_16x16x32_bf16(a[rt], b[ct], acc[rt][ct], 0, 0, 0);
    }

    // Epilogue: bias + scatter. sel is uniform per block (n-tile never crosses a 1024 boundary).
    const int sel = n0 >> 10;
#pragma unroll
    for (int ct = 0; ct < 4; ++ct) {
        const int n = n0 + wn * 64 + ct * 16 + c16;
        const float bv = bias[n];
        const int head = (n >> 6) & 15;
        const int d = n & 63;
#pragma unroll
        for (int rt = 0; rt < 4; ++rt) {
#pragma unroll
            for (int r = 0; r < 4; ++r) {
                const int m = m0 + wm * 64 + rt * 16 + quad * 4 + r;
                const int b_ = m >> 11;
                const int tt = m & 2047;
                const int bh = b_ * NH + head;
                const float v = acc[rt][ct][r] + bv;
                if (sel == 0)      qb[((size_t)bh * TT + tt) * HS + d] = f2bf(v * 0.125f);
                else if (sel == 1) kb[((size_t)bh * TT + tt) * HS + d] = f2bf(v);
                else               vt[((size_t)bh * HS + d) * TT + tt] = f2bf(v);
            }
        }
    }
}

// ---------------- Flash attention v2: Q-tile 128 (32 rows/wave), K-tile 64, padded LDS ----------------
#define SKP 72
#define SVP 72
#define SPP 72
#define NINF (-__builtin_inff())

__global__ __launch_bounds__(256) void k_attn(const unsigned short* __restrict__ qb,
                                              const unsigned short* __restrict__ kb,
                                              const unsigned short* __restrict__ vt,
                                              float* __restrict__ out) {
    __shared__ unsigned short sK[64 * SKP];       // 9216 B  K[tk][d]
    __shared__ unsigned short sV[64 * SVP];       // 9216 B  V^T[d][tk]
    __shared__ unsigned short sP[4 * 32 * SPP];   // 18432 B per-wave P tiles

    const int t = threadIdx.x;
    const int wave = t >> 6, lane = t & 63;
    const int quad = lane >> 4, c16 = lane & 15;
    // load-balance mapping: 16 q-blocks x 32 bh; big tiles first, big+small paired per CU
    const int qi = blockIdx.x >> 5;
    const int qblk = (qi < 8) ? (15 - qi) : (qi - 8);
    const int bh = blockIdx.x & 31;
    const int q0 = qblk * 128;

    const unsigned short* Qp = qb + (size_t)bh * TT * HS;
    const unsigned short* Kp = kb + (size_t)bh * TT * HS;
    const unsigned short* Vp = vt + (size_t)bh * HS * TT;

    const int qw = q0 + wave * 32;                // this wave's 32 q-rows
    bf16x8 qf[2][2];
#pragma unroll
    for (int j = 0; j < 2; ++j)
#pragma unroll
        for (int ks = 0; ks < 2; ++ks)
            qf[j][ks] = *(const bf16x8*)(Qp + (size_t)(qw + j * 16 + c16) * HS + ks * 32 + quad * 8);

    f32x4 o[2][4];
#pragma unroll
    for (int j = 0; j < 2; ++j)
#pragma unroll
        for (int dt = 0; dt < 4; ++dt) o[j][dt] = f32x4{0, 0, 0, 0};
    float mprev[2][4], lsum[2][4];
#pragma unroll
    for (int j = 0; j < 2; ++j)
#pragma unroll
        for (int r = 0; r < 4; ++r) { mprev[j][r] = NINF; lsum[j][r] = 0.f; }

    const int srow = t >> 3, scol = (t & 7) * 8;  // staging: 32 rows x 64 cols per pass
    unsigned short* pw = sP + wave * 32 * SPP;

    const int kiters = (q0 + 128) / 64;
    for (int it = 0; it < kiters; ++it) {
        const int kb0 = it * 64;
        __syncthreads();
        *(bf16x8*)(sK + srow * SKP + scol)        = *(const bf16x8*)(Kp + (size_t)(kb0 + srow) * HS + scol);
        *(bf16x8*)(sK + (32 + srow) * SKP + scol) = *(const bf16x8*)(Kp + (size_t)(kb0 + 32 + srow) * HS + scol);
        *(bf16x8*)(sV + srow * SVP + scol)        = *(const bf16x8*)(Vp + (size_t)srow * TT + kb0 + scol);
        *(bf16x8*)(sV + (32 + srow) * SVP + scol) = *(const bf16x8*)(Vp + (size_t)(32 + srow) * TT + kb0 + scol);
        __syncthreads();
        if (kb0 >= qw + 32) continue;             // tile fully above the diagonal for this wave

        // S = Q K^T  (32 rows x 64 cols per wave)
        f32x4 s[2][4];
#pragma unroll
        for (int j = 0; j < 2; ++j)
#pragma unroll
            for (int cf = 0; cf < 4; ++cf) s[j][cf] = f32x4{0, 0, 0, 0};
#pragma unroll
        for (int cf = 0; cf < 4; ++cf) {
            const bf16x8 kf0 = *(const bf16x8*)(sK + (cf * 16 + c16) * SKP + quad * 8);
            const bf16x8 kf1 = *(const bf16x8*)(sK + (cf * 16 + c16) * SKP + 32 + quad * 8);
#pragma unroll
            for (int j = 0; j < 2; ++j) {
                s[j][cf] = __builtin_amdgcn_mfma_f32_16x16x32_bf16(qf[j][0], kf0, s[j][cf], 0, 0, 0);
                s[j][cf] = __builtin_amdgcn_mfma_f32_16x16x32_bf16(qf[j][1], kf1, s[j][cf], 0, 0, 0);
            }
        }

        const bool needmask = (kb0 + 63) > qw;    // wave-uniform

        // online softmax (scale already folded into Q)
#pragma unroll
        for (int j = 0; j < 2; ++j) {
#pragma unroll
            for (int r = 0; r < 4; ++r) {
                const int row = qw + j * 16 + quad * 4 + r;
                float v0 = s[j][0][r], v1 = s[j][1][r], v2 = s[j][2][r], v3 = s[j][3][r];
                if (needmask) {
                    const int cb = kb0 + c16;
                    v0 = (cb      <= row) ? v0 : NINF;
                    v1 = (cb + 16 <= row) ? v1 : NINF;
                    v2 = (cb + 32 <= row) ? v2 : NINF;
                    v3 = (cb + 48 <= row) ? v3 : NINF;
                }
                float mx = fmaxf(fmaxf(v0, v1), fmaxf(v2, v3));
                mx = fmaxf(mx, __shfl_xor(mx, 1, 16));
                mx = fmaxf(mx, __shfl_xor(mx, 2, 16));
                mx = fmaxf(mx, __shfl_xor(mx, 4, 16));
                mx = fmaxf(mx, __shfl_xor(mx, 8, 16));
                const float mc = fmaxf(mprev[j][r], mx);
                const float al = __expf(mprev[j][r] - mc);
                const float e0 = __expf(v0 - mc);
                const float e1 = __expf(v1 - mc);
                const float e2 = __expf(v2 - mc);
                const float e3 = __expf(v3 - mc);
                float rs = (e0 + e1) + (e2 + e3);
                rs += __shfl_xor(rs, 1, 16);
                rs += __shfl_xor(rs, 2, 16);
                rs += __shfl_xor(rs, 4, 16);
                rs += __shfl_xor(rs, 8, 16);
                lsum[j][r] = lsum[j][r] * al + rs;
                mprev[j][r] = mc;
                o[j][0][r] *= al; o[j][1][r] *= al; o[j][2][r] *= al; o[j][3][r] *= al;
                unsigned short* pr = pw + (j * 16 + quad * 4 + r) * SPP;
                pr[c16]      = f2bf_fast(e0);
                pr[c16 + 16] = f2bf_fast(e1);
                pr[c16 + 32] = f2bf_fast(e2);
                pr[c16 + 48] = f2bf_fast(e3);
            }
        }

        // O += P @ V
        bf16x8 vf[4][2];
#pragma unroll
        for (int dt = 0; dt < 4; ++dt) {
            vf[dt][0] = *(const bf16x8*)(sV + (dt * 16 + c16) * SVP + quad * 8);
            vf[dt][1] = *(const bf16x8*)(sV + (dt * 16 + c16) * SVP + 32 + quad * 8);
        }
#pragma unroll
        for (int rt = 0; rt < 2; ++rt) {
            const bf16x8 pf0 = *(const bf16x8*)(pw + (rt * 16 + c16) * SPP + quad * 8);
            const bf16x8 pf1 = *(const bf16x8*)(pw + (rt * 16 + c16) * SPP + 32 + quad * 8);
#pragma unroll
            for (int dt = 0; dt < 4; ++dt) {
                o[rt][dt] = __builtin_amdgcn_mfma_f32_16x16x32_bf16(pf0, vf[dt][0], o[rt][dt], 0, 0, 0);
                o[rt][dt] = __builtin_amdgcn_mfma_f32_16x16x32_bf16(pf1, vf[dt][1], o[rt][dt], 0, 0, 0);
            }
        }
    }

    // epilogue: out[b][row][h*64 + d] fp32
    const int b_ = bh >> 4, h_ = bh & 15;
#pragma unroll
    for (int j = 0; j < 2; ++j) {
        float il[4];
#pragma unroll
        for (int r = 0; r < 4; ++r) il[r] = 1.0f / lsum[j][r];
#pragma unroll
        for (int dt = 0; dt < 4; ++dt) {
#pragma unroll
            for (int r = 0; r < 4; ++r) {
                const int row = qw + j * 16 + quad * 4 + r;
                out[((size_t)(b_ * TT + row)) * CC + h_ * HS + dt * 16 + c16] = o[j][dt][r] * il[r];
            }
        }
    }
}

extern "C" void kernel_launch(void* const* d_in, const int* in_sizes, int n_in,
                              void* d_out, int out_size, void* d_ws, size_t ws_size,
                              hipStream_t stream) {
    const float* x    = (const float*)d_in[0];   // [B,T,C] fp32
    const float* W    = (const float*)d_in[1];   // [C,3C] fp32
    const float* bias = (const float*)d_in[2];   // [3C] fp32
    float* out = (float*)d_out;                  // [B,T,C] fp32

    char* ws = (char*)d_ws;
    unsigned short* xb = (unsigned short*)(ws);
    unsigned short* wt = (unsigned short*)(ws + 8388608);
    unsigned short* qb = (unsigned short*)(ws + 8388608 + 6291456);
    unsigned short* kb = (unsigned short*)(ws + 8388608 + 6291456 + 8388608);
    unsigned short* vt = (unsigned short*)(ws + 8388608 + 6291456 + 2 * 8388608);

    k_cast<<<dim3(MM * CC / (256 * 4)), dim3(256), 0, stream>>>(x, xb);
    k_transpose_w<<<dim3(N3C / 32, CC / 32), dim3(256), 0, stream>>>(W, wt);
    k_gemm_qkv<<<dim3(N3C / 128, MM / 128), dim3(256), 0, stream>>>(xb, wt, bias, qb, kb, vt);
    k_attn<<<dim3(16 * 32), dim3(256), 0, stream>>>(qb, kb, vt, out);
}

// Round 3
// 204.064 us; speedup vs baseline: 1.5805x; 1.1602x over previous
//
#include <hip/hip_runtime.h>
#include <hip/hip_bf16.h>
#include <math.h>

// Problem constants (B=2, T=2048, C=1024, NH=16, HS=64)
#define BB   2
#define TT   2048
#define CC   1024
#define NH   16
#define HS   64
#define N3C  3072   // 3*C
#define MM   4096   // B*T

typedef __attribute__((ext_vector_type(8))) short bf16x8;
typedef __attribute__((ext_vector_type(4))) float f32x4;

#define NINF (-__builtin_inff())
#define QSCALE 0.1803368801111704f   /* 0.125 * log2(e) : softmax done in exp2 domain */

__device__ __forceinline__ unsigned short f2bf(float f) {
    unsigned int u = __builtin_bit_cast(unsigned int, f);
    unsigned int r = u + 0x7fffu + ((u >> 16) & 1u);   // RNE
    return (unsigned short)(r >> 16);
}

// cheap round-to-nearest (no tie-to-even) — used only for P in [0,1]
__device__ __forceinline__ unsigned short f2bf_fast(float f) {
    unsigned int u = __builtin_bit_cast(unsigned int, f);
    return (unsigned short)((u + 0x8000u) >> 16);
}

// async 16B global -> LDS (dst must be wave-uniform base + lane*16)
__device__ __forceinline__ void gl_lds16(const unsigned short* g, unsigned short* l) {
    __builtin_amdgcn_global_load_lds(
        (const __attribute__((address_space(1))) unsigned int*)g,
        (__attribute__((address_space(3))) unsigned int*)l, 16, 0, 0);
}

// ---------------- cast x (fp32) -> xb (bf16) ----------------
__global__ __launch_bounds__(256) void k_cast(const float* __restrict__ x,
                                              unsigned short* __restrict__ xb) {
    int i = (blockIdx.x * 256 + threadIdx.x) * 4;
    float4 v = *(const float4*)(x + i);
    ushort4 o;
    o.x = f2bf(v.x); o.y = f2bf(v.y); o.z = f2bf(v.z); o.w = f2bf(v.w);
    *(ushort4*)(xb + i) = o;
}

// ---------------- transpose+cast W [K=1024, N=3072] -> Wt [N, K] bf16 ----------------
__global__ __launch_bounds__(256) void k_transpose_w(const float* __restrict__ W,
                                                     unsigned short* __restrict__ Wt) {
    __shared__ float tile[32][33];
    const int n0 = blockIdx.x * 32;
    const int k0 = blockIdx.y * 32;
    const int t = threadIdx.x;
    {
        int kr = t >> 3, ns = (t & 7) * 4;
        float4 v = *(const float4*)(W + (size_t)(k0 + kr) * N3C + n0 + ns);
        tile[kr][ns + 0] = v.x; tile[kr][ns + 1] = v.y;
        tile[kr][ns + 2] = v.z; tile[kr][ns + 3] = v.w;
    }
    __syncthreads();
    {
        int nr = t >> 3, ks = (t & 7) * 4;
        ushort4 o;
        o.x = f2bf(tile[ks + 0][nr]);
        o.y = f2bf(tile[ks + 1][nr]);
        o.z = f2bf(tile[ks + 2][nr]);
        o.w = f2bf(tile[ks + 3][nr]);
        *(ushort4*)(Wt + (size_t)(n0 + nr) * CC + k0 + ks) = o;
    }
}

// ---------------- GEMM (m97 structure): 128x128 tile, BK=32, global_load_lds staging ----------------
// qkv = xb @ Wt^T + bias. Q scaled by 0.125*log2e. V-blocks (n0>=2048) computed transposed
// (swapped mfma operands) so vt [bh,d,t] stores are lane-contiguous in t.
__global__ __launch_bounds__(256) void k_gemm_qkv(const unsigned short* __restrict__ xb,
                                                  const unsigned short* __restrict__ wt,
                                                  const float* __restrict__ bias,
                                                  unsigned short* __restrict__ qb,
                                                  unsigned short* __restrict__ kb,
                                                  unsigned short* __restrict__ vt) {
    __shared__ unsigned short sA[128 * 32];   // 8 KB
    __shared__ unsigned short sB[128 * 32];   // 8 KB
    const int t = threadIdx.x;
    const int wave = t >> 6, lane = t & 63;
    const int quad = lane >> 4, c16 = lane & 15;
    const int wm = wave >> 1, wn = wave & 1;
    const int m0 = blockIdx.y * 128;
    const int n0 = blockIdx.x * 128;
    const int sel = n0 >> 10;                 // block-uniform: 0=q, 1=k, 2=v
    const bool vswap = (sel == 2);

    f32x4 acc[4][4];
#pragma unroll
    for (int i = 0; i < 4; ++i)
#pragma unroll
        for (int j = 0; j < 4; ++j) acc[i][j] = f32x4{0, 0, 0, 0};

    const int srow = wave * 16 + (lane >> 2);
    const int scol = (lane & 3) * 8;
    const unsigned short* gA = xb + (size_t)(m0 + srow) * CC + scol;
    const unsigned short* gB = wt + (size_t)(n0 + srow) * CC + scol;
    unsigned short* lA = sA + wave * 512 + lane * 8;
    unsigned short* lB = sB + wave * 512 + lane * 8;

    for (int k0 = 0; k0 < CC; k0 += 32) {
        __syncthreads();
        gl_lds16(gA + k0, lA);
        gl_lds16(gA + k0 + (size_t)64 * CC, lA + 2048);
        gl_lds16(gB + k0, lB);
        gl_lds16(gB + k0 + (size_t)64 * CC, lB + 2048);
        __syncthreads();
        bf16x8 a[4], b[4];
#pragma unroll
        for (int rt = 0; rt < 4; ++rt)
            a[rt] = *(const bf16x8*)(sA + (wm * 64 + rt * 16 + c16) * 32 + quad * 8);
#pragma unroll
        for (int ct = 0; ct < 4; ++ct)
            b[ct] = *(const bf16x8*)(sB + (wn * 64 + ct * 16 + c16) * 32 + quad * 8);
        if (!vswap) {
#pragma unroll
            for (int rt = 0; rt < 4; ++rt)
#pragma unroll
                for (int ct = 0; ct < 4; ++ct)
                    acc[rt][ct] = __builtin_amdgcn_mfma_f32_16x16x32_bf16(a[rt], b[ct], acc[rt][ct], 0, 0, 0);
        } else {
#pragma unroll
            for (int rt = 0; rt < 4; ++rt)
#pragma unroll
                for (int ct = 0; ct < 4; ++ct)
                    acc[rt][ct] = __builtin_amdgcn_mfma_f32_16x16x32_bf16(b[ct], a[rt], acc[rt][ct], 0, 0, 0);
        }
    }

    if (!vswap) {
        // acc[rt][ct]: row m = wm*64+rt*16+quad*4+r, col n = wn*64+ct*16+c16
#pragma unroll
        for (int ct = 0; ct < 4; ++ct) {
            const int n = n0 + wn * 64 + ct * 16 + c16;
            const float bv = bias[n];
            const int head = (n >> 6) & 15;
            const int d = n & 63;
#pragma unroll
            for (int rt = 0; rt < 4; ++rt) {
#pragma unroll
                for (int r = 0; r < 4; ++r) {
                    const int m = m0 + wm * 64 + rt * 16 + quad * 4 + r;
                    const int b_ = m >> 11;
                    const int tt = m & 2047;
                    const int bh = b_ * NH + head;
                    const float v = acc[rt][ct][r] + bv;
                    if (sel == 0)      qb[((size_t)bh * TT + tt) * HS + d] = f2bf(v * QSCALE);
                    else               kb[((size_t)bh * TT + tt) * HS + d] = f2bf(v);
                }
            }
        }
    } else {
        // transposed: acc[rt][ct]: n = wn*64+ct*16+quad*4+r (d), m = wm*64+rt*16+c16 (t)
#pragma unroll
        for (int ct = 0; ct < 4; ++ct) {
            const float4 bv4 = *(const float4*)(bias + n0 + wn * 64 + ct * 16 + quad * 4);
#pragma unroll
            for (int r = 0; r < 4; ++r) {
                const int n = n0 + wn * 64 + ct * 16 + quad * 4 + r;
                const int head = (n >> 6) & 15;
                const int d = n & 63;
                const float bv = ((const float*)&bv4)[r];
#pragma unroll
                for (int rt = 0; rt < 4; ++rt) {
                    const int m = m0 + wm * 64 + rt * 16 + c16;
                    const int b_ = m >> 11;
                    const int tt = m & 2047;
                    const int bh = b_ * NH + head;
                    vt[((size_t)bh * HS + d) * TT + tt] = f2bf(acc[rt][ct][r] + bv);
                }
            }
        }
    }
}

// ---------------- Flash attention v3: 1 wave/block, 32 q-rows, K-tile 64, no barriers ----------------
// S^T = mfma(K,Q): lane owns q = lane&15 -> in-lane softmax rows; O^T = mfma(V,P).
#define SPP 68   // P row stride (elements); 34 words -> conflict-free b64 writes / b128 reads

__global__ __launch_bounds__(64) void k_attn(const unsigned short* __restrict__ qb,
                                             const unsigned short* __restrict__ kb,
                                             const unsigned short* __restrict__ vt,
                                             float* __restrict__ out) {
    __shared__ unsigned short sP[32 * SPP];   // 4352 B, per-wave (1 wave/block)

    const int lane = threadIdx.x;
    const int quad = lane >> 4, c16 = lane & 15;
    const int qi = blockIdx.x >> 5;
    const int qblk = 63 - qi;                 // largest-work blocks dispatched first
    const int bh = blockIdx.x & 31;
    const int qw = qblk * 32;

    const unsigned short* Qp = qb + (size_t)bh * TT * HS;
    const unsigned short* Kp = kb + (size_t)bh * TT * HS;
    const unsigned short* Vp = vt + (size_t)bh * HS * TT;

    // Q fragments (B-operand for S^T): n = q = qw + j*16 + c16, kdim = d
    bf16x8 qf[2][2];
#pragma unroll
    for (int j = 0; j < 2; ++j)
#pragma unroll
        for (int ks = 0; ks < 2; ++ks)
            qf[j][ks] = *(const bf16x8*)(Qp + (size_t)(qw + j * 16 + c16) * HS + ks * 32 + quad * 8);

    f32x4 o[4][2];                            // O^T: [dt (m: d)][j (n: q)]
#pragma unroll
    for (int dt = 0; dt < 4; ++dt)
#pragma unroll
        for (int j = 0; j < 2; ++j) o[dt][j] = f32x4{0, 0, 0, 0};
    float mprev[2] = {NINF, NINF}, lsum[2] = {0.f, 0.f};

    // per-lane global bases: K-frag m=k_row=c16, kdim=d=quad*8; V-frag m=d=c16, kdim=t=quad*8
    const unsigned short* kbase = Kp + (size_t)c16 * HS + quad * 8;
    const unsigned short* vbase = Vp + (size_t)c16 * TT + quad * 8;

    const int kiters = qw / 64 + 1;
    for (int it = 0; it < kiters; ++it) {
        const int kb0 = it * 64;
        bf16x8 kf[4][2], vf[4][2];
#pragma unroll
        for (int mt = 0; mt < 4; ++mt) {
            kf[mt][0] = *(const bf16x8*)(kbase + (size_t)(kb0 + mt * 16) * HS);
            kf[mt][1] = *(const bf16x8*)(kbase + (size_t)(kb0 + mt * 16) * HS + 32);
        }
#pragma unroll
        for (int dt = 0; dt < 4; ++dt) {
            vf[dt][0] = *(const bf16x8*)(vbase + (size_t)dt * 16 * TT + kb0);
            vf[dt][1] = *(const bf16x8*)(vbase + (size_t)dt * 16 * TT + kb0 + 32);
        }

        // S^T [k=64 rows][q=32 cols]: s[mt][j], element: k=kb0+mt*16+quad*4+r, q=qw+j*16+c16
        f32x4 s[4][2];
#pragma unroll
        for (int mt = 0; mt < 4; ++mt)
#pragma unroll
            for (int j = 0; j < 2; ++j) s[mt][j] = f32x4{0, 0, 0, 0};
#pragma unroll
        for (int mt = 0; mt < 4; ++mt)
#pragma unroll
            for (int j = 0; j < 2; ++j) {
                s[mt][j] = __builtin_amdgcn_mfma_f32_16x16x32_bf16(kf[mt][0], qf[j][0], s[mt][j], 0, 0, 0);
                s[mt][j] = __builtin_amdgcn_mfma_f32_16x16x32_bf16(kf[mt][1], qf[j][1], s[mt][j], 0, 0, 0);
            }

        const bool needmask = (it == kiters - 1);
#pragma unroll
        for (int j = 0; j < 2; ++j) {
            const int q = qw + j * 16 + c16;
            if (needmask) {
#pragma unroll
                for (int mt = 0; mt < 4; ++mt)
#pragma unroll
                    for (int r = 0; r < 4; ++r) {
                        const int k = kb0 + mt * 16 + quad * 4 + r;
                        if (k > q) s[mt][j][r] = NINF;
                    }
            }
            // in-lane max over 16 values + 2 shuffles (quad dim)
            float mx = NINF;
#pragma unroll
            for (int mt = 0; mt < 4; ++mt)
                mx = fmaxf(mx, fmaxf(fmaxf(s[mt][j][0], s[mt][j][1]), fmaxf(s[mt][j][2], s[mt][j][3])));
            mx = fmaxf(mx, __shfl_xor(mx, 16));
            mx = fmaxf(mx, __shfl_xor(mx, 32));
            const float mc = fmaxf(mprev[j], mx);
            const float al = exp2f(mprev[j] - mc);
            mprev[j] = mc;
            float rs = 0.f;
#pragma unroll
            for (int mt = 0; mt < 4; ++mt) {
                float p0 = exp2f(s[mt][j][0] - mc);
                float p1 = exp2f(s[mt][j][1] - mc);
                float p2 = exp2f(s[mt][j][2] - mc);
                float p3 = exp2f(s[mt][j][3] - mc);
                rs += (p0 + p1) + (p2 + p3);
                ushort4 pk;
                pk.x = f2bf_fast(p0); pk.y = f2bf_fast(p1);
                pk.z = f2bf_fast(p2); pk.w = f2bf_fast(p3);
                *(ushort4*)(sP + (j * 16 + c16) * SPP + mt * 16 + quad * 4) = pk;
            }
            rs += __shfl_xor(rs, 16);
            rs += __shfl_xor(rs, 32);
            lsum[j] = lsum[j] * al + rs;
#pragma unroll
            for (int dt = 0; dt < 4; ++dt) o[dt][j] *= al;
        }

        // P fragments (B-operand for O^T): n = q = j*16+c16, kdim = k = ks*32+quad*8..+8
        bf16x8 pf[2][2];
#pragma unroll
        for (int j = 0; j < 2; ++j)
#pragma unroll
            for (int ks = 0; ks < 2; ++ks)
                pf[j][ks] = *(const bf16x8*)(sP + (j * 16 + c16) * SPP + ks * 32 + quad * 8);
#pragma unroll
        for (int dt = 0; dt < 4; ++dt)
#pragma unroll
            for (int j = 0; j < 2; ++j) {
                o[dt][j] = __builtin_amdgcn_mfma_f32_16x16x32_bf16(vf[dt][0], pf[j][0], o[dt][j], 0, 0, 0);
                o[dt][j] = __builtin_amdgcn_mfma_f32_16x16x32_bf16(vf[dt][1], pf[j][1], o[dt][j], 0, 0, 0);
            }
    }

    // epilogue: O^T lane holds q = qw+j*16+c16, d = dt*16+quad*4+r  -> float4 stores
    const int b_ = bh >> 4, h_ = bh & 15;
#pragma unroll
    for (int j = 0; j < 2; ++j) {
        const float il = 1.0f / lsum[j];
        const int q = qw + j * 16 + c16;
        float* orow = out + ((size_t)(b_ * TT + q)) * CC + h_ * HS;
#pragma unroll
        for (int dt = 0; dt < 4; ++dt) {
            float4 w;
            w.x = o[dt][j][0] * il; w.y = o[dt][j][1] * il;
            w.z = o[dt][j][2] * il; w.w = o[dt][j][3] * il;
            *(float4*)(orow + dt * 16 + quad * 4) = w;
        }
    }
}

extern "C" void kernel_launch(void* const* d_in, const int* in_sizes, int n_in,
                              void* d_out, int out_size, void* d_ws, size_t ws_size,
                              hipStream_t stream) {
    const float* x    = (const float*)d_in[0];   // [B,T,C] fp32
    const float* W    = (const float*)d_in[1];   // [C,3C] fp32
    const float* bias = (const float*)d_in[2];   // [3C] fp32
    float* out = (float*)d_out;                  // [B,T,C] fp32

    char* ws = (char*)d_ws;
    unsigned short* xb = (unsigned short*)(ws);
    unsigned short* wt = (unsigned short*)(ws + 8388608);
    unsigned short* qb = (unsigned short*)(ws + 8388608 + 6291456);
    unsigned short* kb = (unsigned short*)(ws + 8388608 + 6291456 + 8388608);
    unsigned short* vt = (unsigned short*)(ws + 8388608 + 6291456 + 2 * 8388608);

    k_cast<<<dim3(MM * CC / (256 * 4)), dim3(256), 0, stream>>>(x, xb);
    k_transpose_w<<<dim3(N3C / 32, CC / 32), dim3(256), 0, stream>>>(W, wt);
    k_gemm_qkv<<<dim3(N3C / 128, MM / 128), dim3(256), 0, stream>>>(xb, wt, bias, qb, kb, vt);
    k_attn<<<dim3(64 * 32), dim3(64), 0, stream>>>(qb, kb, vt, out);
}